// Round 3
// baseline (111.597 us; speedup 1.0000x reference)
//
#include <hip/hip_runtime.h>

// QConv2d v7: occupancy lever. v6b ran at 1.6 TB/s write with 8 waves/CU;
// the poison-fill runs 6.2 TB/s at 32 waves/CU — identical 0.78 GB/s/wave.
// Write BW scales with resident waves => split each batch across 2 blocks
// (grid 512, block h owns strips {2h,2h+1}), giving 2 blocks/CU = 16 waves.
// Producers duplicate the cheap A-C contraction (+~2us VALU, rho re-read is
// L3-served). LDS 69.6KB x2 = 139KB <= 160KB; launch_bounds(512,4) pins
// VGPR <= 128 so 4 waves/SIMD co-reside. All else identical to v6b.

#define TPB 512

typedef float nfloat4 __attribute__((ext_vector_type(4)));

__global__ __launch_bounds__(TPB, 4) void qconv_fused(
    const float* __restrict__ rho,   // [256][128][128]
    const float* __restrict__ ux,    // [8][8]
    const float* __restrict__ uy,    // [8][8]
    const float* __restrict__ uc,    // [4][4]
    float* __restrict__ out)         // [256][256][256]
{
    __shared__ alignas(16) float L[4][64][68];  // 69632 B

    const int tid  = threadIdx.x;
    const int bid  = blockIdx.x;
    const int b    = bid >> 1;      // batch
    const int h    = bid & 1;       // half: strips {2h, 2h+1}
    const int w    = tid >> 6;
    const int lane = tid & 63;
    const int pyp  = lane >> 3, qyp = lane & 7;   // producer post-transpose identity

    // epilogue work identity: 512 = 16 qg x 2 cs-half x 16 sp-local
    const int qg  = tid & 15;
    const int csh = (tid >> 4) & 1;
    const int spl = tid >> 5;                     // 0..15

    float e0[4], e1[4];
#pragma unroll
    for (int c = 0; c < 4; ++c) { e0[c] = uc[c*4+2]; e1[c] = uc[c*4+3]; }
    float* ob = out + (size_t)b * 65536;

    float X[64];  // single in-place state; producers keep it live through strips

    if (w < 4) {  // producer waves
        const int c1 = w >> 1, c2 = w & 1;
        const int px = lane >> 3, qx = lane & 7;
        const float* rb = rho + (size_t)b * 16384
                        + (size_t)((c1 << 6) + (px << 3)) * 128 + (c2 << 6) + (qx << 3);

        // load X[py][qy]: 16 x b128
#pragma unroll
        for (int py = 0; py < 8; ++py) {
            float4 lo = *(const float4*)(rb + py * 128);
            float4 hi = *(const float4*)(rb + py * 128 + 4);
            X[py*8+0]=lo.x; X[py*8+1]=lo.y; X[py*8+2]=lo.z; X[py*8+3]=lo.w;
            X[py*8+4]=hi.x; X[py*8+5]=hi.y; X[py*8+6]=hi.z; X[py*8+7]=hi.w;
        }

        // Stage A: contract qy (row-local, in-place): X[py][j] = sum_k uy[j][k] X[py][k]
#pragma unroll
        for (int r = 0; r < 8; ++r) {
            float t[8];
#pragma unroll
            for (int j = 0; j < 8; ++j) {
                float a = 0.f;
#pragma unroll
                for (int k = 0; k < 8; ++k) a += uy[j*8+k] * X[r*8+k];
                t[j] = a;
            }
#pragma unroll
            for (int j = 0; j < 8; ++j) X[r*8+j] = t[j];
        }

        // Stage B: contract py (col-local, in-place): X[i][c] = sum_k uy[i][k] X[k][c]
#pragma unroll
        for (int cc = 0; cc < 8; ++cc) {
            float t[8];
#pragma unroll
            for (int i = 0; i < 8; ++i) {
                float a = 0.f;
#pragma unroll
                for (int k = 0; k < 8; ++k) a += uy[i*8+k] * X[k*8+cc];
                t[i] = a;
            }
#pragma unroll
            for (int i = 0; i < 8; ++i) X[i*8+cc] = t[i];
        }

        // wave-private transpose via LDS slice w, XOR-swizzled columns
        // (row-stride 68 == 4 mod 32; swizzle spreads same-(lane&7) lanes over
        // all 8 bank quads -> conflict-free b128 reads; 16B alignment kept).
#pragma unroll
        for (int e = 0; e < 64; ++e)
            L[w][e][lane ^ (((e >> 3) & 7) << 2)] = X[e];
        __asm__ volatile("s_waitcnt lgkmcnt(0)" ::: "memory");  // DS in-order per wave
        {
            const int sw = ((lane >> 3) & 7) << 2;
#pragma unroll
            for (int f4 = 0; f4 < 16; ++f4) {
                float4 v = *(const float4*)&L[w][lane][(f4 * 4) ^ sw];
                X[f4*4+0]=v.x; X[f4*4+1]=v.y; X[f4*4+2]=v.z; X[f4*4+3]=v.w;
            }
        }

        // Stage C: contract qx (row-local, in-place): X[p][j] = sum_k ux[j][k] X[p][k]
#pragma unroll
        for (int p = 0; p < 8; ++p) {
            float t[8];
#pragma unroll
            for (int j = 0; j < 8; ++j) {
                float a = 0.f;
#pragma unroll
                for (int k = 0; k < 8; ++k) a += ux[j*8+k] * X[p*8+k];
                t[j] = a;
            }
#pragma unroll
            for (int j = 0; j < 8; ++j) X[p*8+j] = t[j];
        }
    }

    // strip loop over this block's 2 strips: producers finish W rows 2s,2s+1
    // (Stage D); one lgkm-only barrier per strip; stores never vmcnt-drained.
#pragma unroll
    for (int s2 = 0; s2 < 2; ++s2) {
        const int s = 2*h + s2;
        if (w < 4) {
#pragma unroll
            for (int i2 = 0; i2 < 2; ++i2) {
                const int i = 2*s + i2;   // px'
#pragma unroll
                for (int j = 0; j < 8; ++j) {
                    float acc = 0.f;
#pragma unroll
                    for (int k = 0; k < 8; ++k) acc += ux[i*8+k] * X[k*8+j];
                    L[w][i*8+pyp][j*8+qyp] = acc;   // plain (unswizzled) W region
                }
            }
        }
        // LDS-visibility barrier only: lgkmcnt(0) + raw s_barrier (no vmcnt drain;
        // asm "memory" fences pin LDS ops to their side, rule #18).
        __asm__ volatile("s_waitcnt lgkmcnt(0)" ::: "memory");
        __builtin_amdgcn_s_barrier();
        __asm__ volatile("" ::: "memory");

        const int sp = 16*s + spl;
        float4 wv[4];
#pragma unroll
        for (int ww = 0; ww < 4; ++ww) wv[ww] = *(const float4*)&L[ww][sp][qg * 4];
#pragma unroll
        for (int c = 0; c < 4; ++c) {
#pragma unroll
            for (int cs2 = 0; cs2 < 2; ++cs2) {
                const int cs = 2*csh + cs2;
                const float k00 = e0[c]*e0[cs], k01 = e0[c]*e1[cs];
                const float k10 = e1[c]*e0[cs], k11 = e1[c]*e1[cs];
                nfloat4 v;
                v.x = k00*wv[0].x + k01*wv[1].x + k10*wv[2].x + k11*wv[3].x;
                v.y = k00*wv[0].y + k01*wv[1].y + k10*wv[2].y + k11*wv[3].y;
                v.z = k00*wv[0].z + k01*wv[1].z + k10*wv[2].z + k11*wv[3].z;
                v.w = k00*wv[0].w + k01*wv[1].w + k10*wv[2].w + k11*wv[3].w;
                __builtin_nontemporal_store(v,
                    (nfloat4*)&ob[(size_t)((c*64 + sp) * 256 + cs*64 + qg*4)]);
            }
        }
    }
}

extern "C" void kernel_launch(void* const* d_in, const int* in_sizes, int n_in,
                              void* d_out, int out_size, void* d_ws, size_t ws_size,
                              hipStream_t stream) {
    const float* rho = (const float*)d_in[0];
    const float* ux  = (const float*)d_in[1];
    const float* uy  = (const float*)d_in[2];
    const float* uc  = (const float*)d_in[3];
    float* out = (float*)d_out;
    qconv_fused<<<dim3(512), dim3(TPB), 0, stream>>>(rho, ux, uy, uc, out);
}

// Round 4
// 96.089 us; speedup vs baseline: 1.1614x; 1.1614x over previous
//
#include <hip/hip_runtime.h>

// QConv2d v8: v7's 2-blocks-per-batch split (grid 512, block h owns strips
// {2h,2h+1}) with the SPILL FIXED: __launch_bounds__(512,2) — on this toolchain
// the 2nd arg acts as blocks/CU; 4 forced a 64-VGPR budget and spilled X[64] to
// scratch (v7: VGPR=64, WRITE_SIZE 146MB = out 65.5MB + ~81MB spill). Arg 2
// restores the proven 128-VGPR budget (v6b: VGPR=108, zero spill). Runtime
// residency is resource-limited: LDS 69.6KB*2=139<=160KB, VGPR 108*4w=432<=512
// per SIMD -> 2 blocks/CU = 16 waves/CU actually co-reside.
// Evidence: write BW scales with resident waves (8w->1.6 TB/s, 16w->4.2 TB/s
// incl. spill junk, fill@32w->6.2 TB/s). Compulsory 0.9e8 B at 4.2 TB/s ~= 22us.

#define TPB 512

typedef float nfloat4 __attribute__((ext_vector_type(4)));

__global__ __launch_bounds__(TPB, 2) void qconv_fused(
    const float* __restrict__ rho,   // [256][128][128]
    const float* __restrict__ ux,    // [8][8]
    const float* __restrict__ uy,    // [8][8]
    const float* __restrict__ uc,    // [4][4]
    float* __restrict__ out)         // [256][256][256]
{
    __shared__ alignas(16) float L[4][64][68];  // 69632 B

    const int tid  = threadIdx.x;
    const int bid  = blockIdx.x;
    const int b    = bid >> 1;      // batch
    const int h    = bid & 1;       // half: strips {2h, 2h+1}
    const int w    = tid >> 6;
    const int lane = tid & 63;
    const int pyp  = lane >> 3, qyp = lane & 7;   // producer post-transpose identity

    // epilogue work identity: 512 = 16 qg x 2 cs-half x 16 sp-local
    const int qg  = tid & 15;
    const int csh = (tid >> 4) & 1;
    const int spl = tid >> 5;                     // 0..15

    float e0[4], e1[4];
#pragma unroll
    for (int c = 0; c < 4; ++c) { e0[c] = uc[c*4+2]; e1[c] = uc[c*4+3]; }
    float* ob = out + (size_t)b * 65536;

    float X[64];  // single in-place state; producers keep it live through strips

    if (w < 4) {  // producer waves
        const int c1 = w >> 1, c2 = w & 1;
        const int px = lane >> 3, qx = lane & 7;
        const float* rb = rho + (size_t)b * 16384
                        + (size_t)((c1 << 6) + (px << 3)) * 128 + (c2 << 6) + (qx << 3);

        // load X[py][qy]: 16 x b128
#pragma unroll
        for (int py = 0; py < 8; ++py) {
            float4 lo = *(const float4*)(rb + py * 128);
            float4 hi = *(const float4*)(rb + py * 128 + 4);
            X[py*8+0]=lo.x; X[py*8+1]=lo.y; X[py*8+2]=lo.z; X[py*8+3]=lo.w;
            X[py*8+4]=hi.x; X[py*8+5]=hi.y; X[py*8+6]=hi.z; X[py*8+7]=hi.w;
        }

        // Stage A: contract qy (row-local, in-place): X[py][j] = sum_k uy[j][k] X[py][k]
#pragma unroll
        for (int r = 0; r < 8; ++r) {
            float t[8];
#pragma unroll
            for (int j = 0; j < 8; ++j) {
                float a = 0.f;
#pragma unroll
                for (int k = 0; k < 8; ++k) a += uy[j*8+k] * X[r*8+k];
                t[j] = a;
            }
#pragma unroll
            for (int j = 0; j < 8; ++j) X[r*8+j] = t[j];
        }

        // Stage B: contract py (col-local, in-place): X[i][c] = sum_k uy[i][k] X[k][c]
#pragma unroll
        for (int cc = 0; cc < 8; ++cc) {
            float t[8];
#pragma unroll
            for (int i = 0; i < 8; ++i) {
                float a = 0.f;
#pragma unroll
                for (int k = 0; k < 8; ++k) a += uy[i*8+k] * X[k*8+cc];
                t[i] = a;
            }
#pragma unroll
            for (int i = 0; i < 8; ++i) X[i*8+cc] = t[i];
        }

        // wave-private transpose via LDS slice w, XOR-swizzled columns
        // (row-stride 68 == 4 mod 32; swizzle spreads same-(lane&7) lanes over
        // all 8 bank quads -> conflict-free b128 reads; 16B alignment kept).
#pragma unroll
        for (int e = 0; e < 64; ++e)
            L[w][e][lane ^ (((e >> 3) & 7) << 2)] = X[e];
        __asm__ volatile("s_waitcnt lgkmcnt(0)" ::: "memory");  // DS in-order per wave
        {
            const int sw = ((lane >> 3) & 7) << 2;
#pragma unroll
            for (int f4 = 0; f4 < 16; ++f4) {
                float4 v = *(const float4*)&L[w][lane][(f4 * 4) ^ sw];
                X[f4*4+0]=v.x; X[f4*4+1]=v.y; X[f4*4+2]=v.z; X[f4*4+3]=v.w;
            }
        }

        // Stage C: contract qx (row-local, in-place): X[p][j] = sum_k ux[j][k] X[p][k]
#pragma unroll
        for (int p = 0; p < 8; ++p) {
            float t[8];
#pragma unroll
            for (int j = 0; j < 8; ++j) {
                float a = 0.f;
#pragma unroll
                for (int k = 0; k < 8; ++k) a += ux[j*8+k] * X[p*8+k];
                t[j] = a;
            }
#pragma unroll
            for (int j = 0; j < 8; ++j) X[p*8+j] = t[j];
        }
    }

    // strip loop over this block's 2 strips: producers finish W rows 2s,2s+1
    // (Stage D); one lgkm-only barrier per strip; stores never vmcnt-drained.
#pragma unroll
    for (int s2 = 0; s2 < 2; ++s2) {
        const int s = 2*h + s2;
        if (w < 4) {
#pragma unroll
            for (int i2 = 0; i2 < 2; ++i2) {
                const int i = 2*s + i2;   // px'
#pragma unroll
                for (int j = 0; j < 8; ++j) {
                    float acc = 0.f;
#pragma unroll
                    for (int k = 0; k < 8; ++k) acc += ux[i*8+k] * X[k*8+j];
                    L[w][i*8+pyp][j*8+qyp] = acc;   // plain (unswizzled) W region
                }
            }
        }
        // LDS-visibility barrier only: lgkmcnt(0) + raw s_barrier (no vmcnt drain;
        // asm "memory" fences pin LDS ops to their side, rule #18).
        __asm__ volatile("s_waitcnt lgkmcnt(0)" ::: "memory");
        __builtin_amdgcn_s_barrier();
        __asm__ volatile("" ::: "memory");

        const int sp = 16*s + spl;
        float4 wv[4];
#pragma unroll
        for (int ww = 0; ww < 4; ++ww) wv[ww] = *(const float4*)&L[ww][sp][qg * 4];
#pragma unroll
        for (int c = 0; c < 4; ++c) {
#pragma unroll
            for (int cs2 = 0; cs2 < 2; ++cs2) {
                const int cs = 2*csh + cs2;
                const float k00 = e0[c]*e0[cs], k01 = e0[c]*e1[cs];
                const float k10 = e1[c]*e0[cs], k11 = e1[c]*e1[cs];
                nfloat4 v;
                v.x = k00*wv[0].x + k01*wv[1].x + k10*wv[2].x + k11*wv[3].x;
                v.y = k00*wv[0].y + k01*wv[1].y + k10*wv[2].y + k11*wv[3].y;
                v.z = k00*wv[0].z + k01*wv[1].z + k10*wv[2].z + k11*wv[3].z;
                v.w = k00*wv[0].w + k01*wv[1].w + k10*wv[2].w + k11*wv[3].w;
                __builtin_nontemporal_store(v,
                    (nfloat4*)&ob[(size_t)((c*64 + sp) * 256 + cs*64 + qg*4)]);
            }
        }
    }
}

extern "C" void kernel_launch(void* const* d_in, const int* in_sizes, int n_in,
                              void* d_out, int out_size, void* d_ws, size_t ws_size,
                              hipStream_t stream) {
    const float* rho = (const float*)d_in[0];
    const float* ux  = (const float*)d_in[1];
    const float* uy  = (const float*)d_in[2];
    const float* uc  = (const float*)d_in[3];
    float* out = (float*)d_out;
    qconv_fused<<<dim3(512), dim3(TPB), 0, stream>>>(rho, ux, uy, uc, out);
}